// Round 10
// baseline (193.889 us; speedup 1.0000x reference)
//
#include <hip/hip_runtime.h>

// Self-attention block (non-local): B=8, C=256, H=W=64 -> N=4096, dk=64.
// out = x + gamma * softmax((Wq x)^T (Wk x) / 8) applied to (Wv x).
// Pipeline: prep (weights->bf16, fold log2e/8 into Wq) -> proj (MFMA GEMM,
// in-LDS transpose of x) -> flash.
// R10 flash = R9 + cross-iteration register prefetch: V/K fragments are
// double-buffered (static names vfA/vfB, kfA/kfB; loop unrolled x2) and
// iteration t+1's loads issue at the TOP of region A(t), covered by
// S+exp2+pack+barrier+PV of iteration t.  Loads cannot sink past the
// barrier (full fence); counted vmcnt makes the wait for current K ~zero.
// P in 2x8KB double-buffered swizzled LDS, ONE barrier per iteration.

typedef __attribute__((ext_vector_type(8)))  short short8;
typedef __attribute__((ext_vector_type(4)))  short short4v;
typedef __attribute__((ext_vector_type(16))) float f32x16;
typedef __attribute__((ext_vector_type(4)))  float f32x4;

#define B_   8
#define C_   256
#define N_   4096
#define DK_  64
// log2(e) / sqrt(dk) = 1.4426950408889634 / 8
#define QSCL 0.18033688011112043f

#if defined(__has_builtin)
#if __has_builtin(__builtin_amdgcn_exp2f)
#define EXP2F(x) __builtin_amdgcn_exp2f(x)
#else
#define EXP2F(x) exp2f(x)
#endif
#else
#define EXP2F(x) exp2f(x)
#endif

// float -> bf16 bits, round-to-nearest-even (inputs are finite; no NaN path)
__device__ __forceinline__ unsigned short bfb(float f) {
  unsigned u = __builtin_bit_cast(unsigned, f);
  unsigned r = (u + 0x7fffu + ((u >> 16) & 1u)) >> 16;
  return (unsigned short)r;
}

// packed f32x2 -> bf16x2 (low = a, high = b), RNE
__device__ __forceinline__ unsigned cvtpk(float a, float b) {
  unsigned r;
  asm("v_cvt_pk_bf16_f32 %0, %1, %2" : "=v"(r) : "v"(a), "v"(b));
  return r;
}

// ---------------------------------------------------------------------------
// Kernel 1: weight prep.  W'[384][256] bf16 = [Wq*QSCL ; Wk ; Wv], bias'[384].
// ---------------------------------------------------------------------------
__global__ void prep_kernel(const float* __restrict__ Wq, const float* __restrict__ bq,
                            const float* __restrict__ Wk, const float* __restrict__ bk,
                            const float* __restrict__ Wv, const float* __restrict__ bv,
                            unsigned short* __restrict__ Wc, float* __restrict__ biasc) {
  int idx = blockIdx.x * 256 + threadIdx.x;
  if (idx < 384 * 256) {
    int ch = idx >> 8, c = idx & 255;
    float v;
    if (ch < 64)       v = Wq[ch * 256 + c] * QSCL;
    else if (ch < 128) v = Wk[(ch - 64) * 256 + c];
    else               v = Wv[(ch - 128) * 256 + c];
    Wc[idx] = bfb(v);
  }
  if (idx < 384) {
    float bb;
    if (idx < 64)       bb = bq[idx] * QSCL;
    else if (idx < 128) bb = bk[idx - 64];
    else                bb = bv[idx - 128];
    biasc[idx] = bb;
  }
}

// ---------------------------------------------------------------------------
// Kernel 2: projections.  Per (batch, 64-row n-block): stage x[256c][64n]
// transposed into LDS as bf16 (XOR-swizzled), then OUT[n][ch] = Xt * W'^T via
// 32x32x16 bf16 MFMA.  Outputs: Qt,Kt [B][N][64] (n-major), V [B][C][N].
// ---------------------------------------------------------------------------
__global__ __launch_bounds__(256, 2) void proj_kernel(
    const float* __restrict__ x, const unsigned short* __restrict__ Wc,
    const float* __restrict__ biasc, unsigned short* __restrict__ Qt,
    unsigned short* __restrict__ Kt, unsigned short* __restrict__ V) {
  __shared__ unsigned short XT[64 * 256];  // [n][c] bf16, swizzled, 32 KiB
  const int tid = threadIdx.x;
  const int b = blockIdx.y;
  const int n0 = blockIdx.x * 64;

  // stage: x[b][c][n0+0..63] fp32 -> XT[n][c] bf16 (transpose), swizzle:
  // ushort idx = n*256 + (((c>>3) ^ (n&15))<<3) + (c&7)
  {
    const f32x4* x4 = (const f32x4*)(x + ((size_t)b * C_) * N_ + n0);
    int c = tid >> 4;                  // 0..15 (+16 per pass)
    const int nl = (tid & 15) << 2;    // 0,4,...,60
#pragma unroll
    for (int p = 0; p < 16; ++p, c += 16) {
      f32x4 v = x4[(size_t)c * (N_ / 4) + (nl >> 2)];
#pragma unroll
      for (int i = 0; i < 4; ++i) {
        int n = nl + i;
        XT[n * 256 + ((((c >> 3) ^ (n & 15)) << 3) | (c & 7))] = bfb(v[i]);
      }
    }
  }
  __syncthreads();

  const int lane = tid & 63, li = lane & 31, hi = lane >> 5;
  const int w = tid >> 6;
  const int ch0 = 96 * w;  // this wave's 96 output channels (3 x 32)

  f32x16 acc[2][3];
#pragma unroll
  for (int mt = 0; mt < 2; ++mt)
#pragma unroll
    for (int j = 0; j < 3; ++j)
#pragma unroll
      for (int r = 0; r < 16; ++r) acc[mt][j][r] = 0.f;

  const short8* Wc8 = (const short8*)Wc;
#pragma unroll
  for (int ks = 0; ks < 16; ++ks) {
    // A-frags: lane holds Xt[n=32*mt+li][c=16*ks+8*hi .. +8]
    int chunk = 2 * ks + hi;
    short8 a0 = *(const short8*)&XT[(li) * 256 + ((chunk ^ (li & 15)) << 3)];
    short8 a1 = *(const short8*)&XT[(32 + li) * 256 + ((chunk ^ (li & 15)) << 3)];
#pragma unroll
    for (int j = 0; j < 3; ++j) {
      short8 bf = Wc8[(size_t)(ch0 + 32 * j + li) * 32 + chunk];
      acc[0][j] = __builtin_amdgcn_mfma_f32_32x32x16_bf16(a0, bf, acc[0][j], 0, 0, 0);
      acc[1][j] = __builtin_amdgcn_mfma_f32_32x32x16_bf16(a1, bf, acc[1][j], 0, 0, 0);
    }
  }

  // epilogue: D[row=n][col=ch], row = (r&3)+8*(r>>2)+4*hi + 32*mt, col = li
#pragma unroll
  for (int j = 0; j < 3; ++j) {
    const int chb = ch0 + 32 * j;  // wave-uniform 32-block, never straddles Q/K/V
    const int ch = chb + li;
    const float bias = biasc[ch];
#pragma unroll
    for (int mt = 0; mt < 2; ++mt) {
      if (chb < 64) {
#pragma unroll
        for (int r = 0; r < 16; ++r) {
          int n = n0 + 32 * mt + (r & 3) + 8 * (r >> 2) + 4 * hi;
          Qt[((size_t)(b * N_ + n) << 6) + ch] = bfb(acc[mt][j][r] + bias);
        }
      } else if (chb < 128) {
#pragma unroll
        for (int r = 0; r < 16; ++r) {
          int n = n0 + 32 * mt + (r & 3) + 8 * (r >> 2) + 4 * hi;
          Kt[((size_t)(b * N_ + n) << 6) + (ch - 64)] = bfb(acc[mt][j][r] + bias);
        }
      } else {
        const int cv = ch - 128;
#pragma unroll
        for (int q = 0; q < 4; ++q) {  // 4 consecutive n per 8B store
          short4v pk;
#pragma unroll
          for (int i = 0; i < 4; ++i) pk[i] = (short)bfb(acc[mt][j][4 * q + i] + bias);
          int n = n0 + 32 * mt + 8 * q + 4 * hi;
          *(short4v*)&V[(size_t)(b * C_ + cv) * N_ + n] = pk;
        }
      }
    }
  }
}

// ---------------------------------------------------------------------------
// Kernel 3: attention.  Grid 512 x 256 threads (4 waves).
// b = id & 7 (batch <-> XCD), m0 = (id >> 3) * 64.  kv-block 64, 64 iters,
// loop unrolled x2 with ping-pong register buffers (vfA/vfB, kfA*/kfB*).
// Iter t body: (1) prefetch V/K for t+1 into NXT regs (pinned by asm fence +
// barrier); (2) S for the wave's 16-kv slice x 64 m via 16x16x32 MFMA using
// CUR K regs (wait ~0: loads landed during iter t-1); (3) exp2+cvtpk -> P
// (swizzled LDS, buffer t&1); (4) barrier; (5) PV 16x16x32 from P + CUR V.
// P byte addr: buf*8192 + m*128 + (kvbyte ^ ((m&7)<<4)).
// ---------------------------------------------------------------------------
#define ITER_BODY(VFC, KC0, KC1, VFN, KN0, KN1, PB, TN)                        \
  {                                                                            \
    const int ko_ = (TN) << 6;                                                 \
    const size_t kko_ = (size_t)(TN) * 8192;                                   \
    VFN[0][0] = *(const short8*)(vp0 + ko_);                                   \
    VFN[0][1] = *(const short8*)(vp1 + ko_);                                   \
    VFN[0][2] = *(const short8*)(vp2 + ko_);                                   \
    VFN[0][3] = *(const short8*)(vp3 + ko_);                                   \
    VFN[1][0] = *(const short8*)(vp0 + ko_ + 32);                              \
    VFN[1][1] = *(const short8*)(vp1 + ko_ + 32);                              \
    VFN[1][2] = *(const short8*)(vp2 + ko_ + 32);                              \
    VFN[1][3] = *(const short8*)(vp3 + ko_ + 32);                              \
    KN0 = *(const short8*)(Kp + kko_);                                         \
    KN1 = *(const short8*)(Kp + kko_ + 64);                                    \
    asm volatile("" ::: "memory");                                             \
    char* Pb_ = (char*)P[PB];                                                  \
    _Pragma("unroll") for (int mt = 0; mt < 4; ++mt) {                         \
      f32x4 st = {0.f, 0.f, 0.f, 0.f};                                         \
      st = __builtin_amdgcn_mfma_f32_16x16x32_bf16(KC0, qb[mt][0], st, 0, 0, 0);\
      st = __builtin_amdgcn_mfma_f32_16x16x32_bf16(KC1, qb[mt][1], st, 0, 0, 0);\
      float e0 = EXP2F(st[0]), e1 = EXP2F(st[1]);                              \
      float e2 = EXP2F(st[2]), e3 = EXP2F(st[3]);                              \
      den[mt] += (e0 + e1) + (e2 + e3);                                        \
      unsigned lo_ = cvtpk(e0, e1);                                            \
      unsigned hh_ = cvtpk(e2, e3);                                            \
      unsigned long long vv_ =                                                 \
          (unsigned long long)lo_ | ((unsigned long long)hh_ << 32);           \
      *(unsigned long long*)(Pb_ + (16 * mt + lc) * 128 + pwcol) = vv_;        \
    }                                                                          \
    __syncthreads();                                                           \
    _Pragma("unroll") for (int ks = 0; ks < 2; ++ks) {                         \
      short8 pf_[4];                                                           \
      _Pragma("unroll") for (int t16 = 0; t16 < 4; ++t16)                      \
        pf_[t16] = *(const short8*)(Pb_ + (16 * t16 + lc) * 128 +              \
                                    ((64 * ks + 16 * lg) ^ pkey));             \
      __builtin_amdgcn_s_setprio(1);                                           \
      _Pragma("unroll") for (int ct = 0; ct < 4; ++ct)                         \
        _Pragma("unroll") for (int t16 = 0; t16 < 4; ++t16)                    \
          acc16[t16][ct] = __builtin_amdgcn_mfma_f32_16x16x32_bf16(            \
              pf_[t16], VFC[ks][ct], acc16[t16][ct], 0, 0, 0);                 \
      __builtin_amdgcn_s_setprio(0);                                           \
    }                                                                          \
  }

__global__ __launch_bounds__(256, 2) void flash_kernel(
    const unsigned short* __restrict__ Qt, const unsigned short* __restrict__ Kt,
    const unsigned short* __restrict__ V, const float* __restrict__ x,
    const float* __restrict__ gamma, float* __restrict__ out) {
  __shared__ unsigned short P[2][64 * 64];  // 2 x 8 KiB, swizzled
  __shared__ float den_lds[4][4][16];       // [wave][mt][lc]

  const int tid = threadIdx.x;
  const int lane = tid & 63;
  const int lc = lane & 15, lg = lane >> 4;
  const int w = tid >> 6;
  const int id = blockIdx.x;
  const int b = id & 7;                // batch == XCD (round-robin dispatch)
  const int m0 = (id >> 3) << 6;       // 64-row m-block

  // Q B-frags: qb[mt][ks] = Q[m0+16mt+lc][dk = 32ks+8lg .. +7]
  short8 qb[4][2];
#pragma unroll
  for (int mt = 0; mt < 4; ++mt)
#pragma unroll
    for (int ks = 0; ks < 2; ++ks)
      qb[mt][ks] = *(const short8*)(Qt + ((size_t)b * N_ + m0 + 16 * mt + lc) * 64 +
                                    32 * ks + 8 * lg);

  f32x4 acc16[4][4];  // [t16 m-subtile][ct c-subtile]
#pragma unroll
  for (int t16 = 0; t16 < 4; ++t16)
#pragma unroll
    for (int ct = 0; ct < 4; ++ct)
#pragma unroll
      for (int r = 0; r < 4; ++r) acc16[t16][ct][r] = 0.f;
  float den[4] = {0.f, 0.f, 0.f, 0.f};

  // K base: row kv = kv0 + 16w + lc, dk bytes 16lg + {0,64}; +8192B per iter
  const char* Kp = (const char*)Kt + ((size_t)b * N_ + 16 * w + lc) * 128 + 16 * lg;
  // V row pointers: c = 64w + 16ct + lc, kv elem 8lg
  const unsigned short* vp0 = V + ((size_t)b * C_ + 64 * w + 0  + lc) * N_ + 8 * lg;
  const unsigned short* vp1 = V + ((size_t)b * C_ + 64 * w + 16 + lc) * N_ + 8 * lg;
  const unsigned short* vp2 = V + ((size_t)b * C_ + 64 * w + 32 + lc) * N_ + 8 * lg;
  const unsigned short* vp3 = V + ((size_t)b * C_ + 64 * w + 48 + lc) * N_ + 8 * lg;

  const int pkey = (lc & 7) << 4;      // P swizzle key (m&7 == lc&7)
  const int pwcol = (32 * w + 8 * lg) ^ pkey;  // P-write column byte

  // ping-pong operand buffers
  short8 vfA[2][4], vfB[2][4];
  short8 kfA0, kfA1, kfB0, kfB1;

  // prologue: iteration-0 operands into A
  vfA[0][0] = *(const short8*)(vp0);      vfA[0][1] = *(const short8*)(vp1);
  vfA[0][2] = *(const short8*)(vp2);      vfA[0][3] = *(const short8*)(vp3);
  vfA[1][0] = *(const short8*)(vp0 + 32); vfA[1][1] = *(const short8*)(vp1 + 32);
  vfA[1][2] = *(const short8*)(vp2 + 32); vfA[1][3] = *(const short8*)(vp3 + 32);
  kfA0 = *(const short8*)(Kp);
  kfA1 = *(const short8*)(Kp + 64);

  for (int t = 0; t < 64; t += 2) {
    const int tn1 = t + 1;               // always <= 63
    ITER_BODY(vfA, kfA0, kfA1, vfB, kfB0, kfB1, 0, tn1);
    const int tn2 = (t + 2) & 63;        // wraps only on the final trip
    ITER_BODY(vfB, kfB0, kfB1, vfA, kfA0, kfA1, 1, tn2);
  }

  // ---- den reduction: lg-groups (shfl) then cross-wave (LDS) ----
#pragma unroll
  for (int mt = 0; mt < 4; ++mt) {
    float d = den[mt];
    d += __shfl_xor(d, 16);
    d += __shfl_xor(d, 32);
    if (lg == 0) den_lds[w][mt][lc] = d;
  }
  __syncthreads();

  const float g = gamma[0];
  float ig[4];
#pragma unroll
  for (int mt = 0; mt < 4; ++mt) {
    float dtot = den_lds[0][mt][lc] + den_lds[1][mt][lc] +
                 den_lds[2][mt][lc] + den_lds[3][mt][lc];
    ig[mt] = g / dtot;  // lane's lc: gamma/den for m-row m0+16mt+lc
  }

  // ---- epilogue: lane holds O[m=16t16+4lg+r][c=16ct+lc]; f32x4 over m ----
#pragma unroll
  for (int t16 = 0; t16 < 4; ++t16) {
    f32x4 idn;
#pragma unroll
    for (int r = 0; r < 4; ++r)
      idn[r] = __shfl(ig[t16], 4 * lg + r);
#pragma unroll
    for (int ct = 0; ct < 4; ++ct) {
      size_t off = ((size_t)b * C_ + 64 * w + 16 * ct + lc) * N_ + m0 + 16 * t16 + 4 * lg;
      f32x4 xv = *(const f32x4*)(x + off);
      f32x4 o;
#pragma unroll
      for (int r = 0; r < 4; ++r) o[r] = xv[r] + idn[r] * acc16[t16][ct][r];
      *(f32x4*)(out + off) = o;
    }
  }
}

// ---------------------------------------------------------------------------
extern "C" void kernel_launch(void* const* d_in, const int* in_sizes, int n_in,
                              void* d_out, int out_size, void* d_ws, size_t ws_size,
                              hipStream_t stream) {
  const float* x = (const float*)d_in[0];
  const float* Wq = (const float*)d_in[1];
  const float* bq = (const float*)d_in[2];
  const float* Wk = (const float*)d_in[3];
  const float* bk = (const float*)d_in[4];
  const float* Wv = (const float*)d_in[5];
  const float* bv = (const float*)d_in[6];
  const float* gamma = (const float*)d_in[7];
  float* out = (float*)d_out;

  char* ws = (char*)d_ws;
  unsigned short* Wc = (unsigned short*)(ws);                    // 196608 B
  float* biasc = (float*)(ws + 196608);                          // 1536 B
  unsigned short* Qt = (unsigned short*)(ws + 198144);           // 4 MiB
  unsigned short* Kt = (unsigned short*)(ws + 198144 + 4194304); // 4 MiB
  unsigned short* Vv = (unsigned short*)(ws + 198144 + 8388608); // 16 MiB
  // total ws use: ~25.4 MB

  prep_kernel<<<384, 256, 0, stream>>>(Wq, bq, Wk, bk, Wv, bv, Wc, biasc);
  proj_kernel<<<dim3(64, 8), 256, 0, stream>>>(x, Wc, biasc, Qt, Kt, Vv);
  flash_kernel<<<512, 256, 0, stream>>>(Qt, Kt, Vv, x, gamma, out);
}